// Round 4
// baseline (505.305 us; speedup 1.0000x reference)
//
#include <hip/hip_runtime.h>
#include <cstdint>
#include <cstddef>

typedef __bf16 bf16;
typedef __bf16 bf16x8 __attribute__((ext_vector_type(8)));
typedef float  f32x4  __attribute__((ext_vector_type(4)));
typedef float  f32x8  __attribute__((ext_vector_type(8)));

#define MDIM 2048
#define NDIM 4096
#define KDIM 4096
#define FLOATMAX 3.402823466e38f

// ---------------- fp32 -> bf16 conversion, 16B stores ----------------
__global__ void cvt2_f32_to_bf16(const float* __restrict__ x, const float* __restrict__ w,
                                 bf16* __restrict__ xb, bf16* __restrict__ wb,
                                 int xn8, int wn8) {
    const int stride = gridDim.x * blockDim.x;
    int i = blockIdx.x * blockDim.x + threadIdx.x;
    for (int k = i; k < xn8; k += stride) {
        f32x4 lo = reinterpret_cast<const f32x4*>(x)[2 * k];
        f32x4 hi = reinterpret_cast<const f32x4*>(x)[2 * k + 1];
        f32x8 v = {lo[0], lo[1], lo[2], lo[3], hi[0], hi[1], hi[2], hi[3]};
        reinterpret_cast<bf16x8*>(xb)[k] = __builtin_convertvector(v, bf16x8);
    }
    for (int k = i; k < wn8; k += stride) {
        f32x4 lo = reinterpret_cast<const f32x4*>(w)[2 * k];
        f32x4 hi = reinterpret_cast<const f32x4*>(w)[2 * k + 1];
        f32x8 v = {lo[0], lo[1], lo[2], lo[3], hi[0], hi[1], hi[2], hi[3]};
        reinterpret_cast<bf16x8*>(wb)[k] = __builtin_convertvector(v, bf16x8);
    }
}

// async global->LDS, 16B per lane (HW: wave-uniform LDS base + lane*16)
__device__ __forceinline__ void g2lds16(const bf16* g, bf16* l) {
    __builtin_amdgcn_global_load_lds(
        (const __attribute__((address_space(1))) uint32_t*)g,
        (__attribute__((address_space(3))) uint32_t*)l, 16, 0, 0);
}

// ---------------- MAM main kernel: ONE split per launch ----------------
// Grid (N/128, M/128) = 512 blocks = exactly 2 blocks/CU x 256 CU (one round).
// Block 256 threads = 4 waves in 2(m) x 2(n); wave tile 64x64 = 4x4 MFMA 16x16.
// K per launch = 2048 (one SPLIT) as 32 stages of BK=64 (2 ACCBLOCKs folded via
// v_max3/v_min3). LDS dbuf 64 KB -> 2 blocks/CU; mx+mn (128 AGPR) is the only
// accumulator state. mode 0: out = mx+mn+bias (overwrite). mode 1: out += mx+mn
// (plain RMW; single owner per element, kernel-boundary ordering -> deterministic).
__global__ __launch_bounds__(256, 2) void mam_kernel(
    const bf16* __restrict__ A,   // [M,K] bf16 (x)
    const bf16* __restrict__ B,   // [N,K] bf16 (weight row n = col n of w)
    const float* __restrict__ bias,
    float* __restrict__ out,
    int kbase, int mode)
{
    __shared__ __align__(16) bf16 sA[2][2][128 * 32];  // [parity][accblock-half]
    __shared__ __align__(16) bf16 sB[2][2][128 * 32];

    const int t    = threadIdx.x;
    const int lane = t & 63;
    const int w    = t >> 6;        // 0..3
    const int wm   = (w >> 1) * 64; // 0 or 64
    const int wn   = (w & 1) * 64;  // 0 or 64

    const int m0 = blockIdx.y * 128;
    const int n0 = blockIdx.x * 128;

    // staging: 256 threads x 2 issues cover 128 rows x 32 bf16 per buffer.
    // issue i: row r = i*64 + (t>>2), slot p = t&3; fetch global chunk p ^ ((r>>1)&3)
    const bf16* gAi[2];
    const bf16* gBi[2];
    int ldsOff[2];
#pragma unroll
    for (int i = 0; i < 2; ++i) {
        const int r = i * 64 + (t >> 2);
        const int p = t & 3;
        const int c = p ^ ((r >> 1) & 3);
        gAi[i] = A + (size_t)(m0 + r) * KDIM + kbase + c * 8;
        gBi[i] = B + (size_t)(n0 + r) * KDIM + kbase + c * 8;
        ldsOff[i] = (i * 256 + t) * 8;  // bf16 elements; 16B per thread per issue
    }

    // fragment addressing: row R, chunk q=lane>>4 lives at slot q ^ ((R>>1)&3)
    const int frow = lane & 15;
    const int q    = lane >> 4;
    int offA[4], offB[4];
#pragma unroll
    for (int i = 0; i < 4; ++i) {
        const int RA = wm + i * 16 + frow;
        offA[i] = RA * 32 + (q ^ ((RA >> 1) & 3)) * 8;
        const int RB = wn + i * 16 + frow;
        offB[i] = RB * 32 + (q ^ ((RB >> 1) & 3)) * 8;
    }

    const f32x4 kZero = {0.f, 0.f, 0.f, 0.f};

    f32x4 mx[4][4], mn[4][4];
#pragma unroll
    for (int i = 0; i < 4; ++i)
#pragma unroll
        for (int j = 0; j < 4; ++j) {
            mx[i][j] = (f32x4)(-FLOATMAX);
            mn[i][j] = (f32x4)(FLOATMAX);
        }

    auto prefetch = [&](int s, int pb) {
        const size_t so = (size_t)s * 64;
#pragma unroll
        for (int i = 0; i < 2; ++i) {
            g2lds16(gAi[i] + so,      &sA[pb][0][ldsOff[i]]);
            g2lds16(gAi[i] + so + 32, &sA[pb][1][ldsOff[i]]);
            g2lds16(gBi[i] + so,      &sB[pb][0][ldsOff[i]]);
            g2lds16(gBi[i] + so + 32, &sB[pb][1][ldsOff[i]]);
        }
    };

    auto compute = [&](int pb) {
        bf16x8 aF0[4], aF1[4], bF0[4], bF1[4];
#pragma unroll
        for (int i = 0; i < 4; ++i) {
            aF0[i] = *(const bf16x8*)&sA[pb][0][offA[i]];
            aF1[i] = *(const bf16x8*)&sA[pb][1][offA[i]];
            bF0[i] = *(const bf16x8*)&sB[pb][0][offB[i]];
            bF1[i] = *(const bf16x8*)&sB[pb][1][offB[i]];
        }
#pragma unroll
        for (int i = 0; i < 4; ++i) {
#pragma unroll
            for (int j = 0; j < 4; ++j) {
                f32x4 s0 = __builtin_amdgcn_mfma_f32_16x16x32_bf16(
                    aF0[i], bF0[j], kZero, 0, 0, 0);
                f32x4 s1 = __builtin_amdgcn_mfma_f32_16x16x32_bf16(
                    aF1[i], bF1[j], kZero, 0, 0, 0);
#pragma unroll
                for (int r = 0; r < 4; ++r) {
                    mx[i][j][r] = fmaxf(fmaxf(mx[i][j][r], s0[r]), s1[r]);  // v_max3_f32
                    mn[i][j][r] = fminf(fminf(mn[i][j][r], s0[r]), s1[r]);  // v_min3_f32
                }
            }
        }
    };

    prefetch(0, 0);

#pragma unroll 1
    for (int it = 0; it < 16; ++it) {
        __syncthreads();
        prefetch(2 * it + 1, 1);
        compute(0);
        __syncthreads();
        if (it < 15) prefetch(2 * it + 2, 0);
        compute(1);
    }

    // epilogue: C/D layout col=lane&15, row=(lane>>4)*4+reg
    const int orow = (lane >> 4) * 4;
    const int ocol = lane & 15;
    if (mode == 0) {
#pragma unroll
        for (int j = 0; j < 4; ++j) {
            const int col = n0 + wn + j * 16 + ocol;
            const float bv = bias[col];
#pragma unroll
            for (int i = 0; i < 4; ++i) {
                const int row = m0 + wm + i * 16 + orow;
#pragma unroll
                for (int r = 0; r < 4; ++r)
                    out[(size_t)(row + r) * NDIM + col] = mx[i][j][r] + mn[i][j][r] + bv;
            }
        }
    } else {
#pragma unroll
        for (int j = 0; j < 4; ++j) {
            const int col = n0 + wn + j * 16 + ocol;
#pragma unroll
            for (int i = 0; i < 4; ++i) {
                const int row = m0 + wm + i * 16 + orow;
#pragma unroll
                for (int r = 0; r < 4; ++r) {
                    float* p = &out[(size_t)(row + r) * NDIM + col];
                    *p += mx[i][j][r] + mn[i][j][r];  // single owner: plain RMW is safe
                }
            }
        }
    }
}

extern "C" void kernel_launch(void* const* d_in, const int* in_sizes, int n_in,
                              void* d_out, int out_size, void* d_ws, size_t ws_size,
                              hipStream_t stream) {
    const float* x    = (const float*)d_in[0];  // [M,K]
    const float* wgt  = (const float*)d_in[1];  // [N,K]
    const float* bias = (const float*)d_in[2];  // [N]
    float* out = (float*)d_out;

    bf16* xbf = (bf16*)d_ws;                        // M*K bf16 = 16 MiB
    bf16* wbf = xbf + (size_t)MDIM * KDIM;          // N*K bf16 = 32 MiB

    const int xn8 = (MDIM * KDIM) / 8;
    const int wn8 = (NDIM * KDIM) / 8;
    cvt2_f32_to_bf16<<<dim3(4096), dim3(256), 0, stream>>>(x, wgt, xbf, wbf, xn8, wn8);

    dim3 grid(NDIM / 128, MDIM / 128);  // (32, 16) = 512 blocks = 2/CU x 256 CU
    mam_kernel<<<grid, dim3(256), 0, stream>>>(xbf, wbf, bias, out, 0,    0);  // split 0: overwrite
    mam_kernel<<<grid, dim3(256), 0, stream>>>(xbf, wbf, bias, out, 2048, 1);  // split 1: add
}

// Round 5
// 269.883 us; speedup vs baseline: 1.8723x; 1.8723x over previous
//
#include <hip/hip_runtime.h>
#include <cstdint>
#include <cstddef>

typedef __bf16 bf16;
typedef __bf16 bf16x8 __attribute__((ext_vector_type(8)));
typedef float  f32x4  __attribute__((ext_vector_type(4)));
typedef float  f32x8  __attribute__((ext_vector_type(8)));

#define MDIM 2048
#define NDIM 4096
#define KDIM 4096
#define FLOATMAX 3.402823466e38f

// ---------------- fp32 -> bf16 conversion, 16B stores ----------------
__global__ void cvt2_f32_to_bf16(const float* __restrict__ x, const float* __restrict__ w,
                                 bf16* __restrict__ xb, bf16* __restrict__ wb,
                                 int xn8, int wn8) {
    const int stride = gridDim.x * blockDim.x;
    int i = blockIdx.x * blockDim.x + threadIdx.x;
    for (int k = i; k < xn8; k += stride) {
        f32x4 lo = reinterpret_cast<const f32x4*>(x)[2 * k];
        f32x4 hi = reinterpret_cast<const f32x4*>(x)[2 * k + 1];
        f32x8 v = {lo[0], lo[1], lo[2], lo[3], hi[0], hi[1], hi[2], hi[3]};
        reinterpret_cast<bf16x8*>(xb)[k] = __builtin_convertvector(v, bf16x8);
    }
    for (int k = i; k < wn8; k += stride) {
        f32x4 lo = reinterpret_cast<const f32x4*>(w)[2 * k];
        f32x4 hi = reinterpret_cast<const f32x4*>(w)[2 * k + 1];
        f32x8 v = {lo[0], lo[1], lo[2], lo[3], hi[0], hi[1], hi[2], hi[3]};
        reinterpret_cast<bf16x8*>(wb)[k] = __builtin_convertvector(v, bf16x8);
    }
}

// async global->LDS, 16B per lane (HW: wave-uniform LDS base + lane*16)
__device__ __forceinline__ void g2lds16(const bf16* g, bf16* l) {
    __builtin_amdgcn_global_load_lds(
        (const __attribute__((address_space(1))) uint32_t*)g,
        (__attribute__((address_space(3))) uint32_t*)l, 16, 0, 0);
}

// ---------------- MAM main kernel ----------------
// Block tile 128(m) x 64(n); 256 threads = 4 waves in 2(m) x 2(n); wave tile 64x32
// (R2's proven per-wave shape: 16 MFMA + 12 frag reads per stage).
// LDS 48 KB dbuf -> 3 blocks/CU (144 KB, launch_bounds(256,3), ~145 VGPR) = 12 waves/CU.
// The 2 SPLITS run as two sequential K-phases in-kernel; phase 0 stores mx+mn+bias,
// phase 1 does same-thread RMW out += mx+mn (no atomics, deterministic).
// XCD swizzle: each XCD owns an 8x16 (x,y) sub-grid so the streaming K-window
// (~768 KB) fits the per-XCD 4 MB L2.
__global__ __launch_bounds__(256, 3) void mam_kernel(
    const bf16* __restrict__ A,   // [M,K] bf16 (x)
    const bf16* __restrict__ B,   // [N,K] bf16 (weight row n = col n of w)
    const float* __restrict__ bias,
    float* __restrict__ out)
{
    __shared__ __align__(16) bf16 sA[2][2][128 * 32];  // [parity][half] 32 KB
    __shared__ __align__(16) bf16 sB[2][2][64 * 32];   // [parity][half] 16 KB

    const int t    = threadIdx.x;
    const int lane = t & 63;
    const int w    = t >> 6;        // 0..3
    const int wm   = (w >> 1) * 64; // 0 or 64
    const int wn   = (w & 1) * 32;  // 0 or 32

    // XCD-aware remap: linear id -> xcd = l&7 owns x in [8*xcd, 8*xcd+8), y in [0,16)
    const int l   = blockIdx.y * 64 + blockIdx.x;   // grid (64,16)
    const int xcd = l & 7;
    const int idx = l >> 3;          // 0..127
    const int xg  = xcd * 8 + (idx & 7);   // 0..63
    const int yg  = idx >> 3;              // 0..15
    const int m0 = yg * 128;
    const int n0 = xg * 64;

    // staging (per buffer-half): A 8 KB (2 issues/thread), B 4 KB (1 issue/thread).
    // thread t, issue i: row r, slot p=t&3, fetches global chunk c = p ^ ((r>>1)&3);
    // LDS dest is lane-contiguous (g2lds16 requirement), swizzle lives in the source.
    const bf16* gAi[2];
    int ldsA[2];
#pragma unroll
    for (int i = 0; i < 2; ++i) {
        const int r = i * 64 + (t >> 2);
        const int c = (t & 3) ^ ((r >> 1) & 3);
        gAi[i] = A + (size_t)(m0 + r) * KDIM + c * 8;
        ldsA[i] = (i * 256 + t) * 8;
    }
    const int rB = t >> 2;  // 0..63
    const bf16* gB1 = B + (size_t)(n0 + rB) * KDIM + (((t & 3) ^ ((rB >> 1) & 3))) * 8;
    const int ldsB = t * 8;

    // fragment addressing: row R, chunk q=lane>>4 lives at slot q ^ ((R>>1)&3)
    const int frow = lane & 15;
    const int q    = lane >> 4;
    int offA[4], offB[2];
#pragma unroll
    for (int i = 0; i < 4; ++i) {
        const int RA = wm + i * 16 + frow;
        offA[i] = RA * 32 + (q ^ ((RA >> 1) & 3)) * 8;
    }
#pragma unroll
    for (int j = 0; j < 2; ++j) {
        const int RB = wn + j * 16 + frow;
        offB[j] = RB * 32 + (q ^ ((RB >> 1) & 3)) * 8;
    }

    const f32x4 kZero = {0.f, 0.f, 0.f, 0.f};
    const int orow = (lane >> 4) * 4;
    const int ocol = lane & 15;

#pragma unroll 1
    for (int phase = 0; phase < 2; ++phase) {
        const size_t kb = (size_t)phase * 2048;

        f32x4 mx[4][2], mn[4][2];
#pragma unroll
        for (int i = 0; i < 4; ++i)
#pragma unroll
            for (int j = 0; j < 2; ++j) {
                mx[i][j] = (f32x4)(-FLOATMAX);
                mn[i][j] = (f32x4)(FLOATMAX);
            }

        auto prefetch = [&](int s, int pb) {
            const size_t so = kb + (size_t)s * 64;
#pragma unroll
            for (int i = 0; i < 2; ++i) {
                g2lds16(gAi[i] + so,      &sA[pb][0][ldsA[i]]);
                g2lds16(gAi[i] + so + 32, &sA[pb][1][ldsA[i]]);
            }
            g2lds16(gB1 + so,      &sB[pb][0][ldsB]);
            g2lds16(gB1 + so + 32, &sB[pb][1][ldsB]);
        };

        auto compute = [&](int pb) {
            bf16x8 aF0[4], aF1[4], bF0[2], bF1[2];
#pragma unroll
            for (int i = 0; i < 4; ++i) {
                aF0[i] = *(const bf16x8*)&sA[pb][0][offA[i]];
                aF1[i] = *(const bf16x8*)&sA[pb][1][offA[i]];
            }
#pragma unroll
            for (int j = 0; j < 2; ++j) {
                bF0[j] = *(const bf16x8*)&sB[pb][0][offB[j]];
                bF1[j] = *(const bf16x8*)&sB[pb][1][offB[j]];
            }
#pragma unroll
            for (int i = 0; i < 4; ++i) {
#pragma unroll
                for (int j = 0; j < 2; ++j) {
                    f32x4 s0 = __builtin_amdgcn_mfma_f32_16x16x32_bf16(
                        aF0[i], bF0[j], kZero, 0, 0, 0);
                    f32x4 s1 = __builtin_amdgcn_mfma_f32_16x16x32_bf16(
                        aF1[i], bF1[j], kZero, 0, 0, 0);
#pragma unroll
                    for (int r = 0; r < 4; ++r) {
                        mx[i][j][r] = fmaxf(fmaxf(mx[i][j][r], s0[r]), s1[r]);  // v_max3_f32
                        mn[i][j][r] = fminf(fminf(mn[i][j][r], s0[r]), s1[r]);  // v_min3_f32
                    }
                }
            }
        };

        prefetch(0, 0);

#pragma unroll 1
        for (int it = 0; it < 16; ++it) {
            __syncthreads();
            prefetch(2 * it + 1, 1);
            compute(0);
            __syncthreads();
            if (it < 15) prefetch(2 * it + 2, 0);
            compute(1);
        }

        // epilogue: C/D layout col=lane&15, row=(lane>>4)*4+reg
        if (phase == 0) {
#pragma unroll
            for (int j = 0; j < 2; ++j) {
                const int col = n0 + wn + j * 16 + ocol;
                const float bv = bias[col];
#pragma unroll
                for (int i = 0; i < 4; ++i) {
                    const int row = m0 + wm + i * 16 + orow;
#pragma unroll
                    for (int r = 0; r < 4; ++r)
                        out[(size_t)(row + r) * NDIM + col] = mx[i][j][r] + mn[i][j][r] + bv;
                }
            }
        } else {
#pragma unroll
            for (int j = 0; j < 2; ++j) {
                const int col = n0 + wn + j * 16 + ocol;
#pragma unroll
                for (int i = 0; i < 4; ++i) {
                    const int row = m0 + wm + i * 16 + orow;
#pragma unroll
                    for (int r = 0; r < 4; ++r) {
                        float* p = &out[(size_t)(row + r) * NDIM + col];
                        *p += mx[i][j][r] + mn[i][j][r];  // same thread wrote it: ordered
                    }
                }
            }
        }
    }
}

extern "C" void kernel_launch(void* const* d_in, const int* in_sizes, int n_in,
                              void* d_out, int out_size, void* d_ws, size_t ws_size,
                              hipStream_t stream) {
    const float* x    = (const float*)d_in[0];  // [M,K]
    const float* wgt  = (const float*)d_in[1];  // [N,K]
    const float* bias = (const float*)d_in[2];  // [N]
    float* out = (float*)d_out;

    bf16* xbf = (bf16*)d_ws;                        // M*K bf16 = 16 MiB
    bf16* wbf = xbf + (size_t)MDIM * KDIM;          // N*K bf16 = 32 MiB

    const int xn8 = (MDIM * KDIM) / 8;
    const int wn8 = (NDIM * KDIM) / 8;
    cvt2_f32_to_bf16<<<dim3(4096), dim3(256), 0, stream>>>(x, wgt, xbf, wbf, xn8, wn8);

    dim3 grid(64, 16);  // 1024 blocks of 256 thr; 3 blocks/CU resident
    mam_kernel<<<grid, dim3(256), 0, stream>>>(xbf, wbf, bias, out);
}

// Round 6
// 262.910 us; speedup vs baseline: 1.9220x; 1.0265x over previous
//
#include <hip/hip_runtime.h>
#include <cstdint>
#include <cstddef>

typedef __bf16 bf16;
typedef __bf16 bf16x8 __attribute__((ext_vector_type(8)));
typedef float  f32x4  __attribute__((ext_vector_type(4)));
typedef float  f32x8  __attribute__((ext_vector_type(8)));

#define MDIM 2048
#define NDIM 4096
#define KDIM 4096
#define FLOATMAX 3.402823466e38f

// ---------------- fp32 -> bf16 conversion, 16B stores ----------------
__global__ void cvt2_f32_to_bf16(const float* __restrict__ x, const float* __restrict__ w,
                                 bf16* __restrict__ xb, bf16* __restrict__ wb,
                                 int xn8, int wn8) {
    const int stride = gridDim.x * blockDim.x;
    int i = blockIdx.x * blockDim.x + threadIdx.x;
    for (int k = i; k < xn8; k += stride) {
        f32x4 lo = reinterpret_cast<const f32x4*>(x)[2 * k];
        f32x4 hi = reinterpret_cast<const f32x4*>(x)[2 * k + 1];
        f32x8 v = {lo[0], lo[1], lo[2], lo[3], hi[0], hi[1], hi[2], hi[3]};
        reinterpret_cast<bf16x8*>(xb)[k] = __builtin_convertvector(v, bf16x8);
    }
    for (int k = i; k < wn8; k += stride) {
        f32x4 lo = reinterpret_cast<const f32x4*>(w)[2 * k];
        f32x4 hi = reinterpret_cast<const f32x4*>(w)[2 * k + 1];
        f32x8 v = {lo[0], lo[1], lo[2], lo[3], hi[0], hi[1], hi[2], hi[3]};
        reinterpret_cast<bf16x8*>(wb)[k] = __builtin_convertvector(v, bf16x8);
    }
}

// async global->LDS, 16B per lane (HW: wave-uniform LDS base + lane*16)
__device__ __forceinline__ void g2lds16(const bf16* g, bf16* l) {
    __builtin_amdgcn_global_load_lds(
        (const __attribute__((address_space(1))) uint32_t*)g,
        (__attribute__((address_space(3))) uint32_t*)l, 16, 0, 0);
}

// Raw pipeline barriers: bypass the compiler's vmcnt(0)-before-s_barrier drain.
// vmcnt(6): the 6 loads of the newest prefetch stay in flight across the barrier;
// waits only until the 2-stages-ago prefetch (needed THIS stage) has landed.
__device__ __forceinline__ void pipe_barrier_keep6() {
    asm volatile("s_waitcnt vmcnt(6)\n\ts_barrier" ::: "memory");
}
__device__ __forceinline__ void pipe_barrier_drain() {
    asm volatile("s_waitcnt vmcnt(0)\n\ts_barrier" ::: "memory");
}

// ---------------- MAM main kernel ----------------
// Block tile 128(m) x 64(n); 256 threads = 4 waves in 2(m) x 2(n); wave tile 64x32.
// Full K=4096 as 64 stages of BK=64 (2 ACCBLOCKs, folded with v_max3/v_min3);
// split boundary folds (acc += mx+mn) after stages 31 and 63.
// LDS: TRIPLE buffer, 24 KB/stage (72 KB) -> 2 blocks/CU. Prefetch distance 2 with
// raw vmcnt(6) barriers: global load latency (~900 cyc) is covered by ~2 stage-times
// of compute; vmcnt never drains to 0 inside the K-loop (the m97 structural stall).
// XCD swizzle: each XCD owns an 8x16 (x,y) sub-grid -> streaming K-window ~320 KB
// fits the per-XCD 4 MB L2.
__global__ __launch_bounds__(256, 2) void mam_kernel(
    const bf16* __restrict__ A,   // [M,K] bf16 (x)
    const bf16* __restrict__ B,   // [N,K] bf16 (weight row n = col n of w)
    const float* __restrict__ bias,
    float* __restrict__ out)
{
    __shared__ __align__(16) bf16 sA[3][2][128 * 32];  // [buf][accblock-half] 48 KB
    __shared__ __align__(16) bf16 sB[3][2][64 * 32];   // [buf][accblock-half] 24 KB

    const int t    = threadIdx.x;
    const int lane = t & 63;
    const int w    = t >> 6;        // 0..3
    const int wm   = (w >> 1) * 64; // 0 or 64
    const int wn   = (w & 1) * 32;  // 0 or 32

    // XCD-aware remap: linear id l -> xcd = l&7 owns x in [8*xcd, 8*xcd+8), y in [0,16)
    const int l   = blockIdx.y * 64 + blockIdx.x;   // grid (64,16)
    const int xcd = l & 7;
    const int idx = l >> 3;                // 0..127
    const int xg  = xcd * 8 + (idx & 7);   // 0..63
    const int yg  = idx >> 3;              // 0..15
    const int m0 = yg * 128;
    const int n0 = xg * 64;

    // staging: per buffer-half A is 8 KB (2 issues/thread), B 4 KB (1 issue/thread).
    // thread t, row r, slot p=t&3 fetches global chunk c = p ^ ((r>>1)&3);
    // LDS dest lane-contiguous (g2lds16 requirement), swizzle lives in the source addr.
    const bf16* gAi[2];
    int ldsA[2];
#pragma unroll
    for (int i = 0; i < 2; ++i) {
        const int r = i * 64 + (t >> 2);
        const int c = (t & 3) ^ ((r >> 1) & 3);
        gAi[i] = A + (size_t)(m0 + r) * KDIM + c * 8;
        ldsA[i] = (i * 256 + t) * 8;
    }
    const int rB = t >> 2;  // 0..63
    const bf16* gB1 = B + (size_t)(n0 + rB) * KDIM + ((t & 3) ^ ((rB >> 1) & 3)) * 8;
    const int ldsB = t * 8;

    // fragment addressing: row R, chunk q=lane>>4 lives at slot q ^ ((R>>1)&3)
    const int frow = lane & 15;
    const int q    = lane >> 4;
    int offA[4], offB[2];
#pragma unroll
    for (int i = 0; i < 4; ++i) {
        const int RA = wm + i * 16 + frow;
        offA[i] = RA * 32 + (q ^ ((RA >> 1) & 3)) * 8;
    }
#pragma unroll
    for (int j = 0; j < 2; ++j) {
        const int RB = wn + j * 16 + frow;
        offB[j] = RB * 32 + (q ^ ((RB >> 1) & 3)) * 8;
    }

    const f32x4 kZero = {0.f, 0.f, 0.f, 0.f};

    f32x4 acc[4][2], mx[4][2], mn[4][2];
#pragma unroll
    for (int i = 0; i < 4; ++i)
#pragma unroll
        for (int j = 0; j < 2; ++j) {
            acc[i][j] = kZero;
            mx[i][j] = (f32x4)(-FLOATMAX);
            mn[i][j] = (f32x4)(FLOATMAX);
        }

    auto prefetch = [&](int s, int pb) {
        const size_t so = (size_t)s * 64;
#pragma unroll
        for (int i = 0; i < 2; ++i) {
            g2lds16(gAi[i] + so,      &sA[pb][0][ldsA[i]]);
            g2lds16(gAi[i] + so + 32, &sA[pb][1][ldsA[i]]);
        }
        g2lds16(gB1 + so,      &sB[pb][0][ldsB]);
        g2lds16(gB1 + so + 32, &sB[pb][1][ldsB]);
    };

    auto compute = [&](int pb) {
        bf16x8 aF0[4], aF1[4], bF0[2], bF1[2];
#pragma unroll
        for (int i = 0; i < 4; ++i) {
            aF0[i] = *(const bf16x8*)&sA[pb][0][offA[i]];
            aF1[i] = *(const bf16x8*)&sA[pb][1][offA[i]];
        }
#pragma unroll
        for (int j = 0; j < 2; ++j) {
            bF0[j] = *(const bf16x8*)&sB[pb][0][offB[j]];
            bF1[j] = *(const bf16x8*)&sB[pb][1][offB[j]];
        }
#pragma unroll
        for (int i = 0; i < 4; ++i) {
#pragma unroll
            for (int j = 0; j < 2; ++j) {
                f32x4 s0 = __builtin_amdgcn_mfma_f32_16x16x32_bf16(
                    aF0[i], bF0[j], kZero, 0, 0, 0);
                f32x4 s1 = __builtin_amdgcn_mfma_f32_16x16x32_bf16(
                    aF1[i], bF1[j], kZero, 0, 0, 0);
#pragma unroll
                for (int r = 0; r < 4; ++r) {
                    mx[i][j][r] = fmaxf(fmaxf(mx[i][j][r], s0[r]), s1[r]);  // v_max3_f32
                    mn[i][j][r] = fminf(fminf(mn[i][j][r], s0[r]), s1[r]);  // v_min3_f32
                }
            }
        }
    };

    auto fold = [&]() {
#pragma unroll
        for (int i = 0; i < 4; ++i)
#pragma unroll
            for (int j = 0; j < 2; ++j) {
                acc[i][j] += mx[i][j] + mn[i][j];
                mx[i][j] = (f32x4)(-FLOATMAX);
                mn[i][j] = (f32x4)(FLOATMAX);
            }
    };

    prefetch(0, 0);
    prefetch(1, 1);

    int pb = 0;   // buffer for stage s
    int pf = 2;   // buffer for stage s+2
#pragma unroll 1
    for (int s = 0; s < 64; ++s) {
        if (s < 63) pipe_barrier_keep6();  // wait pf(s) only; pf(s+1) stays in flight
        else        pipe_barrier_drain();  // last stage: nothing newer outstanding
        if (s + 2 < 64) prefetch(s + 2, pf);
        compute(pb);
        if (s == 31 || s == 63) fold();
        pb = (pb == 2) ? 0 : pb + 1;
        pf = (pf == 2) ? 0 : pf + 1;
    }

    // epilogue: C/D layout col=lane&15, row=(lane>>4)*4+reg
    const int orow = (lane >> 4) * 4;
    const int ocol = lane & 15;
#pragma unroll
    for (int j = 0; j < 2; ++j) {
        const int col = n0 + wn + j * 16 + ocol;
        const float bv = bias[col];
#pragma unroll
        for (int i = 0; i < 4; ++i) {
            const int row = m0 + wm + i * 16 + orow;
#pragma unroll
            for (int r = 0; r < 4; ++r)
                out[(size_t)(row + r) * NDIM + col] = acc[i][j][r] + bv;
        }
    }
}

extern "C" void kernel_launch(void* const* d_in, const int* in_sizes, int n_in,
                              void* d_out, int out_size, void* d_ws, size_t ws_size,
                              hipStream_t stream) {
    const float* x    = (const float*)d_in[0];  // [M,K]
    const float* wgt  = (const float*)d_in[1];  // [N,K]
    const float* bias = (const float*)d_in[2];  // [N]
    float* out = (float*)d_out;

    bf16* xbf = (bf16*)d_ws;                        // M*K bf16 = 16 MiB
    bf16* wbf = xbf + (size_t)MDIM * KDIM;          // N*K bf16 = 32 MiB

    const int xn8 = (MDIM * KDIM) / 8;
    const int wn8 = (NDIM * KDIM) / 8;
    cvt2_f32_to_bf16<<<dim3(4096), dim3(256), 0, stream>>>(x, wgt, xbf, wbf, xn8, wn8);

    dim3 grid(64, 16);  // 1024 blocks of 256 thr; 2 blocks/CU resident (72 KB LDS)
    mam_kernel<<<grid, dim3(256), 0, stream>>>(xbf, wbf, bias, out);
}